// Round 3
// baseline (502.647 us; speedup 1.0000x reference)
//
#include <hip/hip_runtime.h>

// ---------------------------------------------------------------------------
// 3-layer GraphSAGE (mean aggregation) on MI355X.
//   CSR build (hist -> scan -> fill), then per layer:
//   k_agg  : atomic-free mean aggregation, one wave per node, float2 lanes,
//            4 neighbors in flight
//   k_gemm : fused out = agg@Wl + h@Wr + b (+ReLU), 64-node x 128-col tiles,
//            K virtual 256 in 8 chunks of 32, conflict-free LDS mapping,
//            register double-buffered staging.
// ---------------------------------------------------------------------------

__global__ void k_hist(const int* __restrict__ dst, int* __restrict__ deg, int E)
{
    int i = blockIdx.x * blockDim.x + threadIdx.x;
    int stride = gridDim.x * blockDim.x;
    for (; i < E; i += stride)
        atomicAdd(&deg[dst[i]], 1);
}

// Single-block exclusive scan of deg[0..n-1] -> rp and cur; rp[n] = total.
__global__ __launch_bounds__(1024) void k_scan(const int* __restrict__ deg,
                                               int* __restrict__ rp,
                                               int* __restrict__ cur, int n)
{
    __shared__ int wsum[16];
    __shared__ int carry_s;
    int tid = threadIdx.x, lane = tid & 63, w = tid >> 6;
    if (tid == 0) carry_s = 0;
    __syncthreads();
    for (int base = 0; base < n; base += 4096) {
        int i = base + tid * 4;
        int4 v = make_int4(0, 0, 0, 0);
        if (i + 3 < n) v = *(const int4*)(deg + i);
        else {
            if (i     < n) v.x = deg[i];
            if (i + 1 < n) v.y = deg[i + 1];
            if (i + 2 < n) v.z = deg[i + 2];
            if (i + 3 < n) v.w = deg[i + 3];
        }
        int t = v.x + v.y + v.z + v.w;
        int s = t;
        #pragma unroll
        for (int d = 1; d < 64; d <<= 1) { int u = __shfl_up(s, d); if (lane >= d) s += u; }
        if (lane == 63) wsum[w] = s;
        __syncthreads();
        if (w == 0 && lane < 16) {
            int u = wsum[lane];
            #pragma unroll
            for (int d = 1; d < 16; d <<= 1) { int y = __shfl_up(u, d); if (lane >= d) u += y; }
            wsum[lane] = u;
        }
        __syncthreads();
        int carry = carry_s;
        int off = carry + (w ? wsum[w - 1] : 0) + (s - t);
        int r0 = off, r1 = r0 + v.x, r2 = r1 + v.y, r3 = r2 + v.z;
        if (i + 3 < n) {
            *(int4*)(rp + i)  = make_int4(r0, r1, r2, r3);
            *(int4*)(cur + i) = make_int4(r0, r1, r2, r3);
        } else {
            if (i     < n) { rp[i]     = r0; cur[i]     = r0; }
            if (i + 1 < n) { rp[i + 1] = r1; cur[i + 1] = r1; }
            if (i + 2 < n) { rp[i + 2] = r2; cur[i + 2] = r2; }
            if (i + 3 < n) { rp[i + 3] = r3; cur[i + 3] = r3; }
        }
        __syncthreads();
        if (tid == 1023) carry_s = carry + wsum[15];
    }
    __syncthreads();
    if (tid == 0) rp[n] = carry_s;
}

__global__ void k_fill(const int* __restrict__ src, const int* __restrict__ dst,
                       int* __restrict__ cur, int* __restrict__ col, int E)
{
    int i = blockIdx.x * blockDim.x + threadIdx.x;
    int stride = gridDim.x * blockDim.x;
    for (; i < E; i += stride) {
        int p = atomicAdd(&cur[dst[i]], 1);
        col[p] = src[i];
    }
}

// Mean aggregation: one wave per node; lane l holds dims 2l, 2l+1.
// 4 neighbor rows in flight to hide L3 latency.
__global__ __launch_bounds__(256) void k_agg(const float* __restrict__ h,
                                             const int* __restrict__ rp,
                                             const int* __restrict__ col,
                                             float* __restrict__ agg, int nNodes)
{
    int gw   = (blockIdx.x * blockDim.x + threadIdx.x) >> 6;
    int lane = threadIdx.x & 63;
    int nw   = (gridDim.x * blockDim.x) >> 6;
    for (int n = gw; n < nNodes; n += nw) {
        int s = rp[n], e = rp[n + 1];
        float a0 = 0.f, a1 = 0.f, b0 = 0.f, b1 = 0.f;
        float c0 = 0.f, c1 = 0.f, d0 = 0.f, d1 = 0.f;
        int i = s;
        for (; i + 4 <= e; i += 4) {
            int e0 = col[i], e1 = col[i + 1], e2 = col[i + 2], e3 = col[i + 3];
            float2 v0 = *(const float2*)(h + (size_t)e0 * 128 + lane * 2);
            float2 v1 = *(const float2*)(h + (size_t)e1 * 128 + lane * 2);
            float2 v2 = *(const float2*)(h + (size_t)e2 * 128 + lane * 2);
            float2 v3 = *(const float2*)(h + (size_t)e3 * 128 + lane * 2);
            a0 += v0.x; a1 += v0.y;
            b0 += v1.x; b1 += v1.y;
            c0 += v2.x; c1 += v2.y;
            d0 += v3.x; d1 += v3.y;
        }
        for (; i < e; ++i) {
            int e0 = col[i];
            float2 v0 = *(const float2*)(h + (size_t)e0 * 128 + lane * 2);
            a0 += v0.x; a1 += v0.y;
        }
        float inv = (e > s) ? (1.f / (float)(e - s)) : 0.f;
        float2 o;
        o.x = ((a0 + b0) + (c0 + d0)) * inv;
        o.y = ((a1 + b1) + (c1 + d1)) * inv;
        *(float2*)(agg + (size_t)n * 128 + lane * 2) = o;
    }
}

// Fused SAGE linear: out = agg @ Wl + h @ Wr + b, optional ReLU.
// Tile: 64 nodes x 128 cols per block. Virtual K = 256 (agg|h) in 8 chunks
// of 32. LDS: inT [32][64] (8KB, transposed) + Wc [32][128] (16KB) = 24KB.
// Lane map: ng = lane&15 (4 nodes), cg = wave*4 + (lane>>4) (8 cols).
//   -> inT read: 16 distinct contiguous 16B addrs / wave = 2-way (free)
//   -> Wc reads: 4 distinct addrs in disjoint 4-bank windows = conflict-free
// Register double-buffer: next chunk's global loads issue before compute.
// hmat/out may alias (in-place rows, block-exclusive) -> no __restrict__.
__global__ __launch_bounds__(256) void k_gemm(const float* __restrict__ agg,
                                              const float* hmat,
                                              const float* __restrict__ Wl,
                                              const float* __restrict__ Wr,
                                              const float* __restrict__ bias,
                                              float* out, int relu, int nNodes)
{
    __shared__ float inT[32 * 64];    // [k][node]  8KB
    __shared__ float Wc[32 * 128];    // [k][col]  16KB
    const int tid  = threadIdx.x;
    const int wave = tid >> 6, l = tid & 63;
    const int ng   = l & 15;               // node group: nodes ng*4 .. ng*4+3
    const int cg   = wave * 4 + (l >> 4);  // col group:  cols  cg*8 .. cg*8+7
    const int node0 = blockIdx.x * 64;

    // staging roles: thread copies 8 floats of one input row + 16 floats of W
    const int sn  = tid >> 2;              // node 0..63
    const int skq = (tid & 3) * 8;         // k offset within chunk
    const int gsn = node0 + sn;

    float acc[4][8];
    #pragma unroll
    for (int a = 0; a < 4; ++a)
        #pragma unroll
        for (int b = 0; b < 8; ++b) acc[a][b] = 0.f;

    float rin[8];
    float rw[16];

    auto stage_load = [&](int ch) {
        const float* src = (ch < 4) ? agg : hmat;
        const int kc = (ch & 3) * 32;
        const float* W = (ch < 4) ? (Wl + kc * 128) : (Wr + kc * 128);
        if (gsn < nNodes) {
            const float4* p = (const float4*)(src + (size_t)gsn * 128 + kc + skq);
            *(float4*)(rin)     = p[0];
            *(float4*)(rin + 4) = p[1];
        } else {
            #pragma unroll
            for (int j = 0; j < 8; ++j) rin[j] = 0.f;
        }
        const float4* W4 = (const float4*)W;
        #pragma unroll
        for (int j = 0; j < 4; ++j)
            *(float4*)(rw + j * 4) = W4[tid + j * 256];
    };
    auto stage_write = [&]() {
        #pragma unroll
        for (int j = 0; j < 8; ++j)
            inT[(skq + j) * 64 + sn] = rin[j];
        float4* Wc4 = (float4*)Wc;
        #pragma unroll
        for (int j = 0; j < 4; ++j)
            Wc4[tid + j * 256] = *(float4*)(rw + j * 4);
    };

    stage_load(0);
    stage_write();
    __syncthreads();

    #pragma unroll 1
    for (int ch = 0; ch < 8; ++ch) {
        if (ch < 7) stage_load(ch + 1);       // issue next chunk's loads early
        #pragma unroll 8
        for (int k = 0; k < 32; ++k) {
            float4 a4 = *(const float4*)(inT + k * 64 + ng * 4);
            float4 w0 = *(const float4*)(Wc + k * 128 + cg * 8);
            float4 w1 = *(const float4*)(Wc + k * 128 + cg * 8 + 4);
            float av[4] = {a4.x, a4.y, a4.z, a4.w};
            float wv[8] = {w0.x, w0.y, w0.z, w0.w, w1.x, w1.y, w1.z, w1.w};
            #pragma unroll
            for (int a = 0; a < 4; ++a)
                #pragma unroll
                for (int b = 0; b < 8; ++b)
                    acc[a][b] = fmaf(av[a], wv[b], acc[a][b]);
        }
        __syncthreads();                       // all waves done reading LDS
        if (ch < 7) {
            stage_write();                     // waits vmcnt internally
            __syncthreads();                   // LDS ready for next chunk
        }
    }

    // epilogue: bias (+ReLU) + store
    float bv[8];
    #pragma unroll
    for (int b = 0; b < 8; ++b) bv[b] = bias[cg * 8 + b];
    #pragma unroll
    for (int a = 0; a < 4; ++a) {
        int gn = node0 + ng * 4 + a;
        if (gn < nNodes) {
            float r[8];
            #pragma unroll
            for (int b = 0; b < 8; ++b) {
                float v = acc[a][b] + bv[b];
                r[b] = relu ? fmaxf(v, 0.f) : v;
            }
            float4* o4 = (float4*)(out + (size_t)gn * 128 + cg * 8);
            o4[0] = *(float4*)(r);
            o4[1] = *(float4*)(r + 4);
        }
    }
}

extern "C" void kernel_launch(void* const* d_in, const int* in_sizes, int n_in,
                              void* d_out, int out_size, void* d_ws, size_t ws_size,
                              hipStream_t stream)
{
    const float* x   = (const float*)d_in[0];
    const int*   ei  = (const int*)d_in[1];
    const float* Wl1 = (const float*)d_in[2];
    const float* b1  = (const float*)d_in[3];
    const float* Wr1 = (const float*)d_in[4];
    const float* Wl2 = (const float*)d_in[5];
    const float* b2  = (const float*)d_in[6];
    const float* Wr2 = (const float*)d_in[7];
    const float* Wl3 = (const float*)d_in[8];
    const float* b3  = (const float*)d_in[9];
    const float* Wr3 = (const float*)d_in[10];
    float* out = (float*)d_out;

    int N = in_sizes[0] / 128;
    int E = in_sizes[1] / 2;
    const int* srcp = ei;        // edge_index[0]
    const int* dstp = ei + E;    // edge_index[1]

    // workspace layout (16B-aligned regions)
    float* A  = (float*)d_ws;                       // agg        N*128 f32
    float* B  = A + (size_t)N * 128;                // h          N*128 f32
    int* deg  = (int*)(B + (size_t)N * 128);        // N ints
    int* rp   = deg + ((N + 3) & ~3);               // N+1 ints
    int* cur  = rp + ((N + 4) & ~3);                // N ints
    int* col  = cur + ((N + 3) & ~3);               // E ints

    hipMemsetAsync(deg, 0, (size_t)N * sizeof(int), stream);
    k_hist<<<1024, 256, 0, stream>>>(dstp, deg, E);
    k_scan<<<1, 1024, 0, stream>>>(deg, rp, cur, N);
    k_fill<<<1024, 256, 0, stream>>>(srcp, dstp, cur, col, E);

    int gb = (N + 63) / 64;
    // layer 1
    k_agg<<<4096, 256, 0, stream>>>(x, rp, col, A, N);
    k_gemm<<<gb, 256, 0, stream>>>(A, x, Wl1, Wr1, b1, B, 1, N);
    // layer 2 (in-place on B: block-exclusive rows, reads precede writes)
    k_agg<<<4096, 256, 0, stream>>>(B, rp, col, A, N);
    k_gemm<<<gb, 256, 0, stream>>>(A, B, Wl2, Wr2, b2, B, 1, N);
    // layer 3
    k_agg<<<4096, 256, 0, stream>>>(B, rp, col, A, N);
    k_gemm<<<gb, 256, 0, stream>>>(A, B, Wl3, Wr3, b3, out, 0, N);
}